// Round 3
// baseline (1359.760 us; speedup 1.0000x reference)
//
#include <hip/hip_runtime.h>

typedef float f32x4 __attribute__((ext_vector_type(4)));

// One block-iteration == one memory row (blockDim.x == D4 == 256, 256 x 16B = 4KB row).
// rel = (row - mi) mod M is WAVE-UNIFORM -> the batch/mem select is a scalar branch
// with SGPR base pointers; lanes just add tid*16B. Both planes fused per row,
// 2-row unroll = 4 independent 16B loads + 4 stores in flight per thread.
__global__ __launch_bounds__(256)
void fused_update(const f32x4* __restrict__ memf,
                  const f32x4* __restrict__ memp,
                  const f32x4* __restrict__ batf,
                  const f32x4* __restrict__ batp,
                  f32x4* __restrict__ outf,
                  f32x4* __restrict__ outp,
                  const float* __restrict__ memc,
                  const float* __restrict__ batc,
                  float* __restrict__ outc,
                  const int* __restrict__ d_mi,
                  int M, int B, int D4) {
    const int mi  = *d_mi;
    const int tid = threadIdx.x;

    // confidence plane: M floats, grid-stride
    for (int c = blockIdx.x * blockDim.x + tid; c < M; c += gridDim.x * blockDim.x) {
        int rel = c - mi; if (rel < 0) rel += M;
        outc[c] = (rel < B) ? batc[rel] : memc[c];
    }

    const int rstride = gridDim.x;

#define ROW_ADDRS(R, SF, SP, DST)                                            \
    int rel##R = (R) - mi; if (rel##R < 0) rel##R += M;                      \
    size_t DST = (size_t)(R) * D4 + tid;                                     \
    const f32x4* SF; const f32x4* SP;                                        \
    if (rel##R < B) { size_t s = (size_t)rel##R * D4 + tid;                  \
                      SF = batf + s; SP = batp + s; }                        \
    else            { SF = memf + DST; SP = memp + DST; }

    int row = blockIdx.x;
    for (; row + rstride < M; row += 2 * rstride) {
        int r1 = row + rstride;
        ROW_ADDRS(row, sf0, sp0, d0)
        ROW_ADDRS(r1,  sf1, sp1, d1)
        f32x4 a = *sf0;          // 4 independent loads issue back-to-back
        f32x4 b = *sp0;
        f32x4 c = *sf1;
        f32x4 d = *sp1;
        outf[d0] = a;
        outp[d0] = b;
        outf[d1] = c;
        outp[d1] = d;
    }
    if (row < M) {
        ROW_ADDRS(row, sf0, sp0, d0)
        f32x4 a = *sf0;
        f32x4 b = *sp0;
        outf[d0] = a;
        outp[d0] = b;
    }
#undef ROW_ADDRS
}

// Single block: mean of B confidences + utilization scalar.
__global__ void mean_and_util(const float* __restrict__ conf,
                              const int* __restrict__ d_mi,
                              const int* __restrict__ d_full,
                              float* __restrict__ out_mean,
                              float* __restrict__ out_util,
                              int B, int M) {
    __shared__ float warp_sums[8];
    float s = 0.0f;
    for (int i = threadIdx.x; i < B; i += blockDim.x) s += conf[i];
    #pragma unroll
    for (int off = 32; off > 0; off >>= 1) s += __shfl_down(s, off);
    int lane = threadIdx.x & 63;
    int wave = threadIdx.x >> 6;
    if (lane == 0) warp_sums[wave] = s;
    __syncthreads();
    if (threadIdx.x == 0) {
        int nwaves = (blockDim.x + 63) >> 6;
        float total = 0.0f;
        for (int w = 0; w < nwaves; ++w) total += warp_sums[w];
        out_mean[0] = total / (float)B;

        int mi = *d_mi;
        int ni = (mi + B) % M;
        bool wrapped = (mi + B) >= M;
        bool full = (*d_full != 0) || wrapped;
        out_util[0] = full ? 1.0f : (float)ni / (float)M;
    }
}

extern "C" void kernel_launch(void* const* d_in, const int* in_sizes, int n_in,
                              void* d_out, int out_size, void* d_ws, size_t ws_size,
                              hipStream_t stream) {
    const float* features     = (const float*)d_in[0];
    const float* predictions  = (const float*)d_in[1];
    const float* confidences  = (const float*)d_in[2];
    const float* mem_feat     = (const float*)d_in[3];
    const float* mem_pred     = (const float*)d_in[4];
    const float* mem_conf     = (const float*)d_in[5];
    const int*   d_mi         = (const int*)d_in[6];
    const int*   d_full       = (const int*)d_in[7];

    const int B  = in_sizes[2];          // 4096
    const int MD = in_sizes[3];          // 102,400,000
    const int M  = in_sizes[5];          // 100,000
    const int D  = MD / M;               // 1024
    const int D4 = D / 4;                // 256 == blockDim

    float* out       = (float*)d_out;
    float* out_feat  = out;
    float* out_pred  = out + (size_t)MD;
    float* out_conf  = out + (size_t)2 * MD;
    float* out_mean  = out_conf + M;
    float* out_util  = out_mean + 1;

    const int blocks = 2048;             // 8 blocks/CU, grid-stride over rows

    fused_update<<<blocks, D4, 0, stream>>>(
        (const f32x4*)mem_feat, (const f32x4*)mem_pred,
        (const f32x4*)features, (const f32x4*)predictions,
        (f32x4*)out_feat, (f32x4*)out_pred,
        mem_conf, confidences, out_conf,
        d_mi, M, B, D4);

    mean_and_util<<<1, 256, 0, stream>>>(confidences, d_mi, d_full,
                                         out_mean, out_util, B, M);
}

// Round 5
// 1256.148 us; speedup vs baseline: 1.0825x; 1.0825x over previous
//
#include <hip/hip_runtime.h>

// One block per memory row: blockDim.x = D/4 (=256) threads, each moves one float4.
// Row `row` of the output = batch[rel] if rel = (row - mi) mod M < B, else mem[row].
// Wave-uniform select; one 16B load + one 16B store per thread; 100k tiny blocks
// give maximal TLP for a pure streaming copy (measured best structure, R0=1249.9us).
__global__ void copy_update_rows(const float4* __restrict__ mem,
                                 const float4* __restrict__ batch,
                                 float4* __restrict__ out,
                                 const int* __restrict__ d_mi,
                                 int M, int B, int D4) {
    int row = blockIdx.x;
    int col = threadIdx.x;
    int rel = row - *d_mi;
    if (rel < 0) rel += M;
    unsigned g = (unsigned)row * (unsigned)D4 + (unsigned)col;
    if (rel < B) {
        out[g] = batch[(unsigned)rel * (unsigned)D4 + (unsigned)col];
    } else {
        out[g] = mem[g];
    }
}

// Conf-plane copy fused with mean+utilization: all blocks copy their slice of the
// M-float conf plane; block 0 additionally reduces the B batch confidences.
__global__ void conf_mean_util(const float* __restrict__ memc,
                               const float* __restrict__ batc,
                               float* __restrict__ outc,
                               const int* __restrict__ d_mi,
                               const int* __restrict__ d_full,
                               float* __restrict__ out_mean,
                               float* __restrict__ out_util,
                               int M, int B) {
    int i = blockIdx.x * blockDim.x + threadIdx.x;
    int mi = *d_mi;
    if (i < M) {
        int rel = i - mi;
        if (rel < 0) rel += M;
        outc[i] = (rel < B) ? batc[rel] : memc[i];
    }

    if (blockIdx.x == 0) {
        __shared__ float warp_sums[4];  // 256 threads / 64 lanes
        float s = 0.0f;
        for (int j = threadIdx.x; j < B; j += blockDim.x) s += batc[j];
        #pragma unroll
        for (int off = 32; off > 0; off >>= 1) s += __shfl_down(s, off);
        int lane = threadIdx.x & 63;
        int wave = threadIdx.x >> 6;
        if (lane == 0) warp_sums[wave] = s;
        __syncthreads();
        if (threadIdx.x == 0) {
            float total = warp_sums[0] + warp_sums[1] + warp_sums[2] + warp_sums[3];
            out_mean[0] = total / (float)B;

            int ni = (mi + B) % M;
            bool wrapped = (mi + B) >= M;
            bool full = (*d_full != 0) || wrapped;
            out_util[0] = full ? 1.0f : (float)ni / (float)M;
        }
    }
}

extern "C" void kernel_launch(void* const* d_in, const int* in_sizes, int n_in,
                              void* d_out, int out_size, void* d_ws, size_t ws_size,
                              hipStream_t stream) {
    const float* features     = (const float*)d_in[0];
    const float* predictions  = (const float*)d_in[1];
    const float* confidences  = (const float*)d_in[2];
    const float* mem_feat     = (const float*)d_in[3];
    const float* mem_pred     = (const float*)d_in[4];
    const float* mem_conf     = (const float*)d_in[5];
    const int*   d_mi         = (const int*)d_in[6];
    const int*   d_full       = (const int*)d_in[7];

    const int B  = in_sizes[2];          // 4096
    const int MD = in_sizes[3];          // 102,400,000
    const int M  = in_sizes[5];          // 100,000
    const int D  = MD / M;               // 1024
    const int D4 = D / 4;                // 256 -> one block per row

    float* out       = (float*)d_out;
    float* out_feat  = out;
    float* out_pred  = out + (size_t)MD;
    float* out_conf  = out + (size_t)2 * MD;
    float* out_mean  = out_conf + M;
    float* out_util  = out_mean + 1;

    copy_update_rows<<<M, D4, 0, stream>>>((const float4*)mem_feat,
                                           (const float4*)features,
                                           (float4*)out_feat, d_mi, M, B, D4);
    copy_update_rows<<<M, D4, 0, stream>>>((const float4*)mem_pred,
                                           (const float4*)predictions,
                                           (float4*)out_pred, d_mi, M, B, D4);
    conf_mean_util<<<(M + 255) / 256, 256, 0, stream>>>(mem_conf, confidences,
                                                        out_conf, d_mi, d_full,
                                                        out_mean, out_util, M, B);
}